// Round 5
// baseline (450.517 us; speedup 1.0000x reference)
//
#include <hip/hip_runtime.h>
#include <math.h>

using short8 = __attribute__((ext_vector_type(8))) short;
using f32x4  = __attribute__((ext_vector_type(4))) float;

__device__ __forceinline__ ushort f2bf(float f) {
    union { float f; uint u; } c; c.f = f;
    uint u = c.u;
    uint r = (u + 0x7FFFu + ((u >> 16) & 1u)) >> 16;
    return (ushort)r;
}
__device__ __forceinline__ float bf2f(ushort h) {
    union { uint u; float f; } c; c.u = ((uint)h) << 16;
    return c.f;
}

// async global->LDS, 16 bytes per lane; lds dest = wave-uniform base + lane*16
__device__ __forceinline__ void gload16(const ushort* g, ushort* l) {
    __builtin_amdgcn_global_load_lds(
        (const __attribute__((address_space(1))) unsigned int*)g,
        (__attribute__((address_space(3))) unsigned int*)l,
        16, 0, 0);
}

// ---------------- weight prep: fp32 -> bf16, fold softmax scale into Wq/bq ---
__global__ __launch_bounds__(256) void prep_weights(
    const float* __restrict__ wq, const float* __restrict__ bq,
    const float* __restrict__ wk, const float* __restrict__ bk,
    const float* __restrict__ wv, const float* __restrict__ wo,
    ushort* __restrict__ Wqk, ushort* __restrict__ Wv, ushort* __restrict__ Wo,
    float* __restrict__ bqk, float scale)
{
    int idx = blockIdx.x * 256 + threadIdx.x;
    if (idx < 1024 * 512) {
        float v = (idx < 262144) ? wq[idx] * scale : wk[idx - 262144];
        Wqk[idx] = f2bf(v);
    }
    if (idx < 262144) {
        Wv[idx] = f2bf(wv[idx]);
        Wo[idx] = f2bf(wo[idx]);
    }
    if (idx < 1024) bqk[idx] = (idx < 512) ? bq[idx] * scale : bk[idx - 512];
}

// ------- GroupNorm: [4,512,4096] fp32 -> bf16 TRANSPOSED hn_t[b][hw][c] -----
__global__ __launch_bounds__(256) void gn_kernel(
    const float* __restrict__ x, const float* __restrict__ gamma,
    const float* __restrict__ beta, ushort* __restrict__ hnt)
{
    int blk = blockIdx.x;          // b*32 + g, 128 total
    int b = blk >> 5, g = blk & 31;
    const float* xp = x + (size_t)blk * 65536;   // group chunk: 16 ch * 4096
    int tid = threadIdx.x;

    float s = 0.f, sq = 0.f;
    for (int i = tid * 4; i < 65536; i += 1024) {
        float4 v = *(const float4*)&xp[i];
        s  += v.x + v.y + v.z + v.w;
        sq += v.x * v.x + v.y * v.y + v.z * v.z + v.w * v.w;
    }
    #pragma unroll
    for (int off = 32; off; off >>= 1) {
        s  += __shfl_xor(s,  off, 64);
        sq += __shfl_xor(sq, off, 64);
    }
    __shared__ float red[8];
    if ((tid & 63) == 0) { red[(tid >> 6) * 2] = s; red[(tid >> 6) * 2 + 1] = sq; }
    __syncthreads();
    float ts = red[0] + red[2] + red[4] + red[6];
    float tq = red[1] + red[3] + red[5] + red[7];
    float mean = ts * (1.f / 65536.f);
    float var  = tq * (1.f / 65536.f) - mean * mean;
    float rstd = rsqrtf(var + 1e-6f);

    float a[16], c[16];
    #pragma unroll
    for (int ch = 0; ch < 16; ++ch) {
        float ga = gamma[g * 16 + ch], be = beta[g * 16 + ch];
        a[ch] = rstd * ga; c[ch] = be - mean * a[ch];
    }

    __shared__ ushort ls[16][256];
    for (int tile = 0; tile < 16; ++tile) {
        int i0 = tile * 256;
        __syncthreads();
        #pragma unroll
        for (int ch = 0; ch < 16; ++ch)
            ls[ch][tid] = f2bf(xp[ch * 4096 + i0 + tid] * a[ch] + c[ch]);
        __syncthreads();
        ushort t[16];
        #pragma unroll
        for (int ch = 0; ch < 16; ++ch) t[ch] = ls[ch][tid];
        size_t dst = ((size_t)b * 4096 + i0 + tid) * 512 + g * 16;
        *(uint4*)&hnt[dst]     = *(const uint4*)&t[0];
        *(uint4*)&hnt[dst + 8] = *(const uint4*)&t[8];
    }
}

// ---------------- softmax over rows of 4096 (in-place, bf16) ----------------
__global__ __launch_bounds__(256) void softmax_kernel(ushort* __restrict__ P)
{
    size_t row = blockIdx.x;
    ushort* p = P + row * 4096;
    int tid = threadIdx.x;

    ushort tmp[16];
    *(uint4*)&tmp[0] = *(const uint4*)&p[tid * 16];
    *(uint4*)&tmp[8] = *(const uint4*)&p[tid * 16 + 8];
    float v[16];
    float mx = -1e30f;
    #pragma unroll
    for (int j = 0; j < 16; ++j) { v[j] = bf2f(tmp[j]); mx = fmaxf(mx, v[j]); }
    #pragma unroll
    for (int off = 32; off; off >>= 1) mx = fmaxf(mx, __shfl_xor(mx, off, 64));
    __shared__ float ls[8];
    if ((tid & 63) == 0) ls[tid >> 6] = mx;
    __syncthreads();
    float m4 = fmaxf(fmaxf(ls[0], ls[1]), fmaxf(ls[2], ls[3]));
    float sum = 0.f;
    #pragma unroll
    for (int j = 0; j < 16; ++j) { v[j] = __expf(v[j] - m4); sum += v[j]; }
    #pragma unroll
    for (int off = 32; off; off >>= 1) sum += __shfl_xor(sum, off, 64);
    if ((tid & 63) == 0) ls[4 + (tid >> 6)] = sum;
    __syncthreads();
    float inv = 1.0f / (ls[4] + ls[5] + ls[6] + ls[7]);
    #pragma unroll
    for (int j = 0; j < 16; ++j) tmp[j] = f2bf(v[j] * inv);
    *(uint4*)&p[tid * 16]     = *(const uint4*)&tmp[0];
    *(uint4*)&p[tid * 16 + 8] = *(const uint4*)&tmp[8];
}

// ---------- NT bf16 MFMA GEMM, 128 x BN x 32 tiles, async staging -----------
// C[m,n] = sum_k A[m,k]*B[n,k]   A: [M][K] lda, B: [N][K] ldb (both K-contig)
// BN in {64,128}. Grid: x = m-tiles, y = n-tiles, z = batch. A-tile sharers
// are gridDim.x apart in linear order; gridDim.x % 8 == 0 puts them on the
// same XCD so the A-tile (e.g. P in the PV GEMM) is L2-shared.
// BIAS: 0 none, 1 row (bias[m]), 2 col (bias[n]).  OUTF32: fp32 out + resid.
template <int BN, int BIAS, bool OUTF32>
__global__ __launch_bounds__(256, 4) void gemm_nt(
    const ushort* __restrict__ Ag, const ushort* __restrict__ Bg,
    ushort* __restrict__ Cb, float* __restrict__ Cf,
    const float* __restrict__ bias, const float* __restrict__ resid,
    int N, int K, int lda, int ldb,
    long sA, long sB, long sC)
{
    constexpr int NT = BN / 32;            // n-fragments per wave
    const int bz = blockIdx.z;
    Ag += (size_t)bz * sA;
    Bg += (size_t)bz * sB;

    const int tid  = threadIdx.x;
    const int wave = tid >> 6, lane = tid & 63;
    const int q = lane >> 4, lr = lane & 15;
    const int m0 = blockIdx.x * 128, n0 = blockIdx.y * BN;
    const int wm = (wave >> 1) * 64, wn = (wave & 1) * (BN / 2);

    // unpadded canonical layout: row-major [row][k], 32 bf16 (64 B) per row
    __shared__ __align__(16) ushort As[128 * 32];
    __shared__ __align__(16) ushort Bs[BN * 32];

    // async staging: wave w stages A rows [32w,32w+32), B rows [BN/4*w, ...)
    const int lrow = lane >> 2;
    const int skc  = (lane & 3) << 3;
    const int arow = wave * 32 + lrow;
    const int brow = wave * (BN / 4) + lrow;
    const size_t aoff0 = (size_t)(m0 + arow) * lda + skc;
    const size_t aoff1 = aoff0 + (size_t)16 * lda;
    const size_t boff0 = (size_t)(n0 + brow) * ldb + skc;
    const size_t boff1 = boff0 + (size_t)16 * ldb;   // used only if BN==128
    ushort* lA0 = &As[wave * 32 * 32];               // wave-uniform bases
    ushort* lA1 = &As[(wave * 32 + 16) * 32];
    ushort* lB0 = &Bs[wave * (BN / 4) * 32];
    ushort* lB1 = &Bs[(wave * (BN / 4) + 16) * 32];

    f32x4 acc[4][NT] = {};

    for (int kb = 0; kb < K; kb += 32) {
        __syncthreads();
        gload16(&Ag[aoff0 + kb], lA0);
        gload16(&Ag[aoff1 + kb], lA1);
        gload16(&Bg[boff0 + kb], lB0);
        if (BN == 128) gload16(&Bg[boff1 + kb], lB1);
        __syncthreads();

        short8 af[4], bfr[NT];
        #pragma unroll
        for (int mt = 0; mt < 4; ++mt)
            af[mt] = *(const short8*)&As[(wm + mt * 16 + lr) * 32 + q * 8];
        #pragma unroll
        for (int nt = 0; nt < NT; ++nt)
            bfr[nt] = *(const short8*)&Bs[(wn + nt * 16 + lr) * 32 + q * 8];
        #pragma unroll
        for (int mt = 0; mt < 4; ++mt)
            #pragma unroll
            for (int nt = 0; nt < NT; ++nt)
                acc[mt][nt] = __builtin_amdgcn_mfma_f32_16x16x32_bf16(
                    af[mt], bfr[nt], acc[mt][nt], 0, 0, 0);
    }

    // ---- epilogue: D row = q*4+t, col = lr (within each 16x16 tile)
    #pragma unroll
    for (int mt = 0; mt < 4; ++mt) {
        int rb = m0 + wm + mt * 16 + q * 4;
        #pragma unroll
        for (int nt = 0; nt < NT; ++nt) {
            int cn = n0 + wn + nt * 16 + lr;
            #pragma unroll
            for (int t = 0; t < 4; ++t) {
                int r = rb + t;
                float v = acc[mt][nt][t];
                if (BIAS == 1) v += bias[r];
                if (BIAS == 2) v += bias[cn];
                size_t o = (size_t)bz * sC + (size_t)r * N + cn;
                if (OUTF32) Cf[o] = v + resid[o];
                else        Cb[o] = f2bf(v);
            }
        }
    }
}

// ---------------- launch -----------------------------------------------------
extern "C" void kernel_launch(void* const* d_in, const int* in_sizes, int n_in,
                              void* d_out, int out_size, void* d_ws, size_t ws_size,
                              hipStream_t stream)
{
    const float* x   = (const float*)d_in[0];
    const float* gnw = (const float*)d_in[1];
    const float* gnb = (const float*)d_in[2];
    const float* wq  = (const float*)d_in[3];
    const float* bq  = (const float*)d_in[4];
    const float* wk  = (const float*)d_in[5];
    const float* bk  = (const float*)d_in[6];
    const float* wv  = (const float*)d_in[7];
    const float* bv  = (const float*)d_in[8];
    const float* wo  = (const float*)d_in[9];
    const float* bo  = (const float*)d_in[10];
    float* out = (float*)d_out;

    char* ws = (char*)d_ws;
    // layout (bytes):
    ushort* hnt = (ushort*)(ws);                 // 16 MB  [b][i][c]
    ushort* QKt = (ushort*)(ws + 16777216);      // 32 MB  [b][i][{q512,k512}]
    ushort* V   = (ushort*)(ws + 50331648);      // 16 MB  [b][c][j]
    ushort* P   = (ushort*)(ws + 67108864);      // 128 MB [b][i][j]
    ushort* Ot  = (ushort*)(ws + 201326592);     // 16 MB  [b][i][c]
    ushort* Wqk = (ushort*)(ws + 218103808);     // 1 MB
    ushort* Wv  = (ushort*)(ws + 219152384);     // 512 KB
    ushort* Wo  = (ushort*)(ws + 219676672);     // 512 KB
    float*  bqk = (float*) (ws + 220200960);     // 4 KB

    const float scale = 1.0f / sqrtf(512.0f);
    const long sHW  = 512L * 4096;     // 2 M elems
    const long sQK  = 4096L * 1024;
    const long sP   = 4096L * 4096;

    prep_weights<<<2048, 256, 0, stream>>>(wq, bq, wk, bk, wv, wo,
                                           Wqk, Wv, Wo, bqk, scale);
    gn_kernel<<<128, 256, 0, stream>>>(x, gnw, gnb, hnt);

    // QKt[i][o] = hn_t[i][c] . Wqk[o][c]  (M=4096, N=1024, K=512), col-bias
    gemm_nt<128, 2, false><<<dim3(32, 8, 4), 256, 0, stream>>>(
        hnt, Wqk, QKt, nullptr, bqk, nullptr,
        1024, 512, 512, 512, sHW, 0L, sQK);

    // V[o][j] = Wv[o][c] . hn_t[j][c]  (M=512, N=4096, K=512), row-bias
    gemm_nt<64, 1, false><<<dim3(4, 64, 4), 256, 0, stream>>>(
        Wv, hnt, V, nullptr, bv, nullptr,
        4096, 512, 512, 512, 0L, sHW, sHW);

    // S[i][j] = Qt[i][c] . Kt[j][c]  (M=N=4096, K=512)
    gemm_nt<128, 0, false><<<dim3(32, 32, 4), 256, 0, stream>>>(
        QKt, QKt + 512, P, nullptr, nullptr, nullptr,
        4096, 512, 1024, 1024, sQK, sQK, sP);

    softmax_kernel<<<16384, 256, 0, stream>>>(P);

    // Ot[i][c] = P[i][j] . V[c][j]  (M=4096, N=512, K=4096)
    // BN=64: grid 1024 blocks -> 4 blocks/CU. The 8 n-sharers of each P-tile
    // are 32 apart in linear order -> same XCD -> P fetched from HBM once.
    gemm_nt<64, 0, false><<<dim3(32, 8, 4), 256, 0, stream>>>(
        P, V, Ot, nullptr, nullptr, nullptr,
        512, 4096, 4096, 4096, sP, sHW, sHW);

    // out[o][i] = x + Wo[o][c] . Ot[i][c] + bo  (M=512, N=4096, K=512), fp32
    gemm_nt<64, 1, true><<<dim3(4, 64, 4), 256, 0, stream>>>(
        Wo, Ot, nullptr, out, bo, x,
        4096, 512, 512, 512, 0L, sHW, sHW);
}

// Round 6
// 393.047 us; speedup vs baseline: 1.1462x; 1.1462x over previous
//
#include <hip/hip_runtime.h>
#include <math.h>

using short8 = __attribute__((ext_vector_type(8))) short;
using f32x4  = __attribute__((ext_vector_type(4))) float;

__device__ __forceinline__ ushort f2bf(float f) {
    union { float f; uint u; } c; c.f = f;
    uint u = c.u;
    uint r = (u + 0x7FFFu + ((u >> 16) & 1u)) >> 16;
    return (ushort)r;
}
__device__ __forceinline__ float bf2f(ushort h) {
    union { uint u; float f; } c; c.u = ((uint)h) << 16;
    return c.f;
}

// async global->LDS, 16 bytes per lane; lds dest = wave-uniform base + lane*16
__device__ __forceinline__ void gload16(const ushort* g, ushort* l) {
    __builtin_amdgcn_global_load_lds(
        (const __attribute__((address_space(1))) unsigned int*)g,
        (__attribute__((address_space(3))) unsigned int*)l,
        16, 0, 0);
}

// ---------------- weight prep: fp32 -> bf16, fold softmax scale into Wq/bq ---
__global__ __launch_bounds__(256) void prep_weights(
    const float* __restrict__ wq, const float* __restrict__ bq,
    const float* __restrict__ wk, const float* __restrict__ bk,
    const float* __restrict__ wv, const float* __restrict__ wo,
    ushort* __restrict__ Wqk, ushort* __restrict__ Wv, ushort* __restrict__ Wo,
    float* __restrict__ bqk, float scale)
{
    int idx = blockIdx.x * 256 + threadIdx.x;
    if (idx < 1024 * 512) {
        float v = (idx < 262144) ? wq[idx] * scale : wk[idx - 262144];
        Wqk[idx] = f2bf(v);
    }
    if (idx < 262144) {
        Wv[idx] = f2bf(wv[idx]);
        Wo[idx] = f2bf(wo[idx]);
    }
    if (idx < 1024) bqk[idx] = (idx < 512) ? bq[idx] * scale : bk[idx - 512];
}

// ------- GroupNorm: [4,512,4096] fp32 -> bf16 TRANSPOSED hn_t[b][hw][c] -----
__global__ __launch_bounds__(256) void gn_kernel(
    const float* __restrict__ x, const float* __restrict__ gamma,
    const float* __restrict__ beta, ushort* __restrict__ hnt)
{
    int blk = blockIdx.x;          // b*32 + g, 128 total
    int b = blk >> 5, g = blk & 31;
    const float* xp = x + (size_t)blk * 65536;   // group chunk: 16 ch * 4096
    int tid = threadIdx.x;

    float s = 0.f, sq = 0.f;
    for (int i = tid * 4; i < 65536; i += 1024) {
        float4 v = *(const float4*)&xp[i];
        s  += v.x + v.y + v.z + v.w;
        sq += v.x * v.x + v.y * v.y + v.z * v.z + v.w * v.w;
    }
    #pragma unroll
    for (int off = 32; off; off >>= 1) {
        s  += __shfl_xor(s,  off, 64);
        sq += __shfl_xor(sq, off, 64);
    }
    __shared__ float red[8];
    if ((tid & 63) == 0) { red[(tid >> 6) * 2] = s; red[(tid >> 6) * 2 + 1] = sq; }
    __syncthreads();
    float ts = red[0] + red[2] + red[4] + red[6];
    float tq = red[1] + red[3] + red[5] + red[7];
    float mean = ts * (1.f / 65536.f);
    float var  = tq * (1.f / 65536.f) - mean * mean;
    float rstd = rsqrtf(var + 1e-6f);

    float a[16], c[16];
    #pragma unroll
    for (int ch = 0; ch < 16; ++ch) {
        float ga = gamma[g * 16 + ch], be = beta[g * 16 + ch];
        a[ch] = rstd * ga; c[ch] = be - mean * a[ch];
    }

    __shared__ ushort ls[16][256];
    for (int tile = 0; tile < 16; ++tile) {
        int i0 = tile * 256;
        __syncthreads();
        #pragma unroll
        for (int ch = 0; ch < 16; ++ch)
            ls[ch][tid] = f2bf(xp[ch * 4096 + i0 + tid] * a[ch] + c[ch]);
        __syncthreads();
        ushort t[16];
        #pragma unroll
        for (int ch = 0; ch < 16; ++ch) t[ch] = ls[ch][tid];
        size_t dst = ((size_t)b * 4096 + i0 + tid) * 512 + g * 16;
        *(uint4*)&hnt[dst]     = *(const uint4*)&t[0];
        *(uint4*)&hnt[dst + 8] = *(const uint4*)&t[8];
    }
}

// ---------------- softmax over rows of 4096 (in-place, bf16) ----------------
__global__ __launch_bounds__(256) void softmax_kernel(ushort* __restrict__ P)
{
    size_t row = blockIdx.x;
    ushort* p = P + row * 4096;
    int tid = threadIdx.x;

    ushort tmp[16];
    *(uint4*)&tmp[0] = *(const uint4*)&p[tid * 16];
    *(uint4*)&tmp[8] = *(const uint4*)&p[tid * 16 + 8];
    float v[16];
    float mx = -1e30f;
    #pragma unroll
    for (int j = 0; j < 16; ++j) { v[j] = bf2f(tmp[j]); mx = fmaxf(mx, v[j]); }
    #pragma unroll
    for (int off = 32; off; off >>= 1) mx = fmaxf(mx, __shfl_xor(mx, off, 64));
    __shared__ float ls[8];
    if ((tid & 63) == 0) ls[tid >> 6] = mx;
    __syncthreads();
    float m4 = fmaxf(fmaxf(ls[0], ls[1]), fmaxf(ls[2], ls[3]));
    float sum = 0.f;
    #pragma unroll
    for (int j = 0; j < 16; ++j) { v[j] = __expf(v[j] - m4); sum += v[j]; }
    #pragma unroll
    for (int off = 32; off; off >>= 1) sum += __shfl_xor(sum, off, 64);
    if ((tid & 63) == 0) ls[4 + (tid >> 6)] = sum;
    __syncthreads();
    float inv = 1.0f / (ls[4] + ls[5] + ls[6] + ls[7]);
    #pragma unroll
    for (int j = 0; j < 16; ++j) tmp[j] = f2bf(v[j] * inv);
    *(uint4*)&p[tid * 16]     = *(const uint4*)&tmp[0];
    *(uint4*)&p[tid * 16 + 8] = *(const uint4*)&tmp[8];
}

// ---- NT bf16 MFMA GEMM, 128x128 tile, BK=64 (two 32-k sub-tiles/barrier) ---
// C[m,n] = sum_k A[m,k]*B[n,k]   A: [M][K] lda, B: [N][K] ldb (both K-contig)
// K must be a multiple of 64. Grid: x = m-tiles, y = n-tiles, z = batch.
// A-tile sharers are gridDim.x apart in linear order; gridDim.x % 8 == 0 puts
// them on the same XCD so the A-tile (P in the PV GEMM) is L2-shared.
// BIAS: 0 none, 1 row (bias[m]), 2 col (bias[n]).  OUTF32: fp32 out + resid.
template <int BIAS, bool OUTF32>
__global__ __launch_bounds__(256, 4) void gemm_nt(
    const ushort* __restrict__ Ag, const ushort* __restrict__ Bg,
    ushort* __restrict__ Cb, float* __restrict__ Cf,
    const float* __restrict__ bias, const float* __restrict__ resid,
    int N, int K, int lda, int ldb,
    long sA, long sB, long sC)
{
    const int bz = blockIdx.z;
    Ag += (size_t)bz * sA;
    Bg += (size_t)bz * sB;

    const int tid  = threadIdx.x;
    const int wave = tid >> 6, lane = tid & 63;
    const int q = lane >> 4, lr = lane & 15;
    const int m0 = blockIdx.x * 128, n0 = blockIdx.y * 128;   // m on X!
    const int wm = (wave >> 1) * 64, wn = (wave & 1) * 64;

    // two k-sub-buffers per operand; each keeps the proven 64B-row layout
    __shared__ __align__(16) ushort As[2][128 * 32];   // 2 x 8 KB
    __shared__ __align__(16) ushort Bs[2][128 * 32];   // 2 x 8 KB

    // async staging: wave w stages rows [32w, 32w+32); 2 insts per sub-buffer
    const int srow = wave * 32 + (lane >> 2);
    const int skc  = (lane & 3) << 3;
    const size_t aoff0 = (size_t)(m0 + srow) * lda + skc;
    const size_t aoff1 = aoff0 + (size_t)16 * lda;
    const size_t boff0 = (size_t)(n0 + srow) * ldb + skc;
    const size_t boff1 = boff0 + (size_t)16 * ldb;
    const int l0 = wave * 1024, l1 = wave * 1024 + 512;   // wave-uniform bases

    f32x4 acc[4][4] = {};

    for (int kb = 0; kb < K; kb += 64) {
        __syncthreads();
        gload16(&Ag[aoff0 + kb],      &As[0][l0]);
        gload16(&Ag[aoff1 + kb],      &As[0][l1]);
        gload16(&Ag[aoff0 + kb + 32], &As[1][l0]);
        gload16(&Ag[aoff1 + kb + 32], &As[1][l1]);
        gload16(&Bg[boff0 + kb],      &Bs[0][l0]);
        gload16(&Bg[boff1 + kb],      &Bs[0][l1]);
        gload16(&Bg[boff0 + kb + 32], &Bs[1][l0]);
        gload16(&Bg[boff1 + kb + 32], &Bs[1][l1]);
        __syncthreads();

        #pragma unroll
        for (int kh = 0; kh < 2; ++kh) {
            short8 af[4], bfr[4];
            #pragma unroll
            for (int mt = 0; mt < 4; ++mt)
                af[mt] = *(const short8*)&As[kh][(wm + mt * 16 + lr) * 32 + q * 8];
            #pragma unroll
            for (int nt = 0; nt < 4; ++nt)
                bfr[nt] = *(const short8*)&Bs[kh][(wn + nt * 16 + lr) * 32 + q * 8];
            #pragma unroll
            for (int mt = 0; mt < 4; ++mt)
                #pragma unroll
                for (int nt = 0; nt < 4; ++nt)
                    acc[mt][nt] = __builtin_amdgcn_mfma_f32_16x16x32_bf16(
                        af[mt], bfr[nt], acc[mt][nt], 0, 0, 0);
        }
    }

    // ---- epilogue: D row = q*4+t, col = lr (within each 16x16 tile)
    #pragma unroll
    for (int mt = 0; mt < 4; ++mt) {
        int rb = m0 + wm + mt * 16 + q * 4;
        #pragma unroll
        for (int nt = 0; nt < 4; ++nt) {
            int cn = n0 + wn + nt * 16 + lr;
            #pragma unroll
            for (int t = 0; t < 4; ++t) {
                int r = rb + t;
                float v = acc[mt][nt][t];
                if (BIAS == 1) v += bias[r];
                if (BIAS == 2) v += bias[cn];
                size_t o = (size_t)bz * sC + (size_t)r * N + cn;
                if (OUTF32) Cf[o] = v + resid[o];
                else        Cb[o] = f2bf(v);
            }
        }
    }
}

// ---------------- launch -----------------------------------------------------
extern "C" void kernel_launch(void* const* d_in, const int* in_sizes, int n_in,
                              void* d_out, int out_size, void* d_ws, size_t ws_size,
                              hipStream_t stream)
{
    const float* x   = (const float*)d_in[0];
    const float* gnw = (const float*)d_in[1];
    const float* gnb = (const float*)d_in[2];
    const float* wq  = (const float*)d_in[3];
    const float* bq  = (const float*)d_in[4];
    const float* wk  = (const float*)d_in[5];
    const float* bk  = (const float*)d_in[6];
    const float* wv  = (const float*)d_in[7];
    const float* bv  = (const float*)d_in[8];
    const float* wo  = (const float*)d_in[9];
    const float* bo  = (const float*)d_in[10];
    float* out = (float*)d_out;

    char* ws = (char*)d_ws;
    // layout (bytes):
    ushort* hnt = (ushort*)(ws);                 // 16 MB  [b][i][c]
    ushort* QKt = (ushort*)(ws + 16777216);      // 32 MB  [b][i][{q512,k512}]
    ushort* V   = (ushort*)(ws + 50331648);      // 16 MB  [b][c][j]
    ushort* P   = (ushort*)(ws + 67108864);      // 128 MB [b][i][j]
    ushort* Ot  = (ushort*)(ws + 201326592);     // 16 MB  [b][i][c]
    ushort* Wqk = (ushort*)(ws + 218103808);     // 1 MB
    ushort* Wv  = (ushort*)(ws + 219152384);     // 512 KB
    ushort* Wo  = (ushort*)(ws + 219676672);     // 512 KB
    float*  bqk = (float*) (ws + 220200960);     // 4 KB

    const float scale = 1.0f / sqrtf(512.0f);
    const long sHW  = 512L * 4096;     // 2 M elems
    const long sQK  = 4096L * 1024;
    const long sP   = 4096L * 4096;

    prep_weights<<<2048, 256, 0, stream>>>(wq, bq, wk, bk, wv, wo,
                                           Wqk, Wv, Wo, bqk, scale);
    gn_kernel<<<128, 256, 0, stream>>>(x, gnw, gnb, hnt);

    // QKt[i][o] = hn_t[i][c] . Wqk[o][c]  (M=4096, N=1024, K=512), col-bias
    gemm_nt<2, false><<<dim3(32, 8, 4), 256, 0, stream>>>(
        hnt, Wqk, QKt, nullptr, bqk, nullptr,
        1024, 512, 512, 512, sHW, 0L, sQK);

    // V[o][j] = Wv[o][c] . hn_t[j][c]  (M=512, N=4096, K=512), row-bias
    gemm_nt<1, false><<<dim3(4, 32, 4), 256, 0, stream>>>(
        Wv, hnt, V, nullptr, bv, nullptr,
        4096, 512, 512, 512, 0L, sHW, sHW);

    // S[i][j] = Qt[i][c] . Kt[j][c]  (M=N=4096, K=512)
    gemm_nt<0, false><<<dim3(32, 32, 4), 256, 0, stream>>>(
        QKt, QKt + 512, P, nullptr, nullptr, nullptr,
        4096, 512, 1024, 1024, sQK, sQK, sP);

    softmax_kernel<<<16384, 256, 0, stream>>>(P);

    // Ot[i][c] = P[i][j] . V[c][j]  (M=4096, N=512, K=4096)
    // grid x=32 m-tiles: the 4 n-sharers of each P-tile are 32 apart in
    // linear order -> same XCD -> P fetched from HBM once, re-read from L2.
    gemm_nt<0, false><<<dim3(32, 4, 4), 256, 0, stream>>>(
        P, V, Ot, nullptr, nullptr, nullptr,
        512, 4096, 4096, 4096, sP, sHW, sHW);

    // out[o][i] = x + Wo[o][c] . Ot[i][c] + bo  (M=512, N=4096, K=512), fp32
    gemm_nt<1, true><<<dim3(4, 32, 4), 256, 0, stream>>>(
        Wo, Ot, nullptr, out, bo, x,
        4096, 512, 512, 512, 0L, sHW, sHW);
}